// Round 9
// baseline (67.924 us; speedup 1.0000x reference)
//
#include <hip/hip_runtime.h>

// Resample 48k -> 10k: up=5, down=24, 481-tap FIR.
// y[5k+d] = sum_{c=0..14,u=0..7} T[c*40+d*8+u] * x[24k-48+8c+u]
// T[c*40+d*8+u] = 5*h[24d+480-5*(8c+u)]  (wave-uniform -> SGPR s_load)
//
// R9: BARRIER-FREE intra-wave pipeline. Every prior kernel fit a zero-overlap
// sum model (VALU+DS+HBM ~= dur). Cause: hipcc emits s_waitcnt vmcnt(0)
// lgkmcnt(0) before EVERY s_barrier (m97 barrier-drain), so any
// __syncthreads between stage and compute serializes each wave's phases --
// R4's prefetch was drained at the next barrier by construction.
// Fix: 1-wave persistent blocks, NO __syncthreads anywhere, double-buffered
// LDS. Per chunk: issue loads(c+1) -> compute(c) -> vmcnt+ds_write(c+1) ->
// store y(c). HBM latency of c+1 hides under compute(c); in-order DS makes
// single-wave LDS correct without barriers.
// Grid 59x32 = 1888 blocks x 16.3 kB LDS -> 10 blocks/CU -> all co-resident.

#define NIN    1440000
#define NOUTR  300000
#define NROWS  32
#define KTOT   60000
#define NCHUNK 938               // ceil(KTOT/64)
#define S      16                // chunks per block
#define NBX    59                // ceil(NCHUNK/S)
#define TILE   1632              // 24*63 + 120
#define NV4    (TILE / 4)        // 408 float4s
#define PADN   2040              // swizzled floats per buffer (1.25x)
#define TAPN   600

__global__ void prep_taps_kernel(const float* __restrict__ h, float* __restrict__ T) {
    int i = blockIdx.x * blockDim.x + threadIdx.x;
    if (i < TAPN) {
        int u = i & 7;
        int d = (i >> 3) % 5;
        int c = i / 40;
        int t = 24 * d + 480 - 5 * (c * 8 + u);
        T[i] = (t >= 0 && t <= 480) ? h[t] * 5.0f : 0.0f;
    }
}

__global__ __launch_bounds__(64) void resample_kernel(
    const float* __restrict__ x, const float* __restrict__ T, float* __restrict__ y)
{
    __shared__ float lds[2 * PADN];
    const int tid   = threadIdx.x;          // 0..63
    const int row   = blockIdx.y;
    const int cbase = blockIdx.x * S;
    const float* __restrict__ xr = x + (size_t)row * NIN;

    float4 pf0, pf1, pf2, pf3, pf4, pf5, pf6;

    auto load_chunk = [&](int c) {          // issue 7 global float4 loads
        const int g0 = 1536 * c - 48;       // multiple of 4 -> 16B-aligned
        if (g0 >= 0 && g0 + TILE <= NIN) {  // uniform fast path
            const float4* __restrict__ p = reinterpret_cast<const float4*>(xr + g0);
            pf0 = p[tid];       pf1 = p[tid + 64];  pf2 = p[tid + 128];
            pf3 = p[tid + 192]; pf4 = p[tid + 256]; pf5 = p[tid + 320];
            if (tid < NV4 - 384) pf6 = p[tid + 384];
        } else {                             // first/last chunks only
            auto ld = [&](int i4) {
                const int g = g0 + 4 * i4; float4 v;
                v.x = ((unsigned)(g + 0) < NIN) ? xr[g + 0] : 0.f;
                v.y = ((unsigned)(g + 1) < NIN) ? xr[g + 1] : 0.f;
                v.z = ((unsigned)(g + 2) < NIN) ? xr[g + 2] : 0.f;
                v.w = ((unsigned)(g + 3) < NIN) ? xr[g + 3] : 0.f;
                return v;
            };
            pf0 = ld(tid);       pf1 = ld(tid + 64);  pf2 = ld(tid + 128);
            pf3 = ld(tid + 192); pf4 = ld(tid + 256); pf5 = ld(tid + 320);
            if (tid < NV4 - 384) pf6 = ld(tid + 384);
        }
    };

    auto write_buf = [&](int b) {           // pad-2-per-8 swizzled stores
        float* __restrict__ L = lds + b * PADN;
        auto st = [&](const float4& v, int i4) {
            const int e = i4 * 4;
            const int m = e + ((e >> 3) << 1);
            *reinterpret_cast<float2*>(L + m)     = make_float2(v.x, v.y);
            *reinterpret_cast<float2*>(L + m + 2) = make_float2(v.z, v.w);
        };
        st(pf0, tid);       st(pf1, tid + 64);  st(pf2, tid + 128);
        st(pf3, tid + 192); st(pf4, tid + 256); st(pf5, tid + 320);
        if (tid < NV4 - 384) st(pf6, tid + 384);
    };

    load_chunk(cbase);
    write_buf(0);

    for (int t = 0; t < S; ++t) {
        const int c = cbase + t;
        if (c >= NCHUNK) break;                       // uniform
        const bool pre = (t + 1 < S) && (c + 1 < NCHUNK);
        if (pre) load_chunk(c + 1);                   // in flight across compute

        float2 acc[5];
        #pragma unroll
        for (int d = 0; d < 5; ++d) acc[d] = make_float2(0.f, 0.f);

        const float* __restrict__ L = lds + (t & 1) * PADN;
        const int base = 30 * tid;                    // swizzled window start
        #pragma unroll
        for (int cc = 0; cc < 15; ++cc) {
            const int m0 = base + 10 * cc;
            const float2 xv0 = *reinterpret_cast<const float2*>(L + m0);
            const float2 xv1 = *reinterpret_cast<const float2*>(L + m0 + 2);
            const float2 xv2 = *reinterpret_cast<const float2*>(L + m0 + 4);
            const float2 xv3 = *reinterpret_cast<const float2*>(L + m0 + 6);
            #pragma unroll
            for (int d = 0; d < 5; ++d) {
                // compile-time skip of all-zero tap groups (cc,d constants)
                if (24 * d + 480 - 40 * cc >= 0 && 24 * d + 445 - 40 * cc <= 480) {
                    const float2* __restrict__ tp =
                        reinterpret_cast<const float2*>(T + cc * 40 + d * 8);
                    const float2 t0 = tp[0], t1 = tp[1], t2 = tp[2], t3 = tp[3];
                    asm("v_pk_fma_f32 %0, %1, %2, %0" : "+v"(acc[d]) : "s"(t0), "v"(xv0));
                    asm("v_pk_fma_f32 %0, %1, %2, %0" : "+v"(acc[d]) : "s"(t1), "v"(xv1));
                    asm("v_pk_fma_f32 %0, %1, %2, %0" : "+v"(acc[d]) : "s"(t2), "v"(xv2));
                    asm("v_pk_fma_f32 %0, %1, %2, %0" : "+v"(acc[d]) : "s"(t3), "v"(xv3));
                }
            }
        }

        if (pre) write_buf((t + 1) & 1);   // vmcnt wait lands here, post-compute

        const int k = 64 * c + tid;
        if (k < KTOT) {
            float* __restrict__ yr = y + (size_t)row * NOUTR + (size_t)5 * k;
            yr[0] = acc[0].x + acc[0].y;
            yr[1] = acc[1].x + acc[1].y;
            yr[2] = acc[2].x + acc[2].y;
            yr[3] = acc[3].x + acc[3].y;
            yr[4] = acc[4].x + acc[4].y;
        }
    }
}

extern "C" void kernel_launch(void* const* d_in, const int* in_sizes, int n_in,
                              void* d_out, int out_size, void* d_ws, size_t ws_size,
                              hipStream_t stream) {
    const float* x = (const float*)d_in[0];
    const float* h = (const float*)d_in[1];   // 481 taps
    float* y = (float*)d_out;                 // 32 x 300000 f32
    float* T = (float*)d_ws;                  // 600 floats of scratch

    prep_taps_kernel<<<3, 256, 0, stream>>>(h, T);
    dim3 grid(NBX, NROWS);                    // 59 x 32 persistent 1-wave blocks
    resample_kernel<<<grid, 64, 0, stream>>>(x, T, y);
}

// Round 11
// 49.273 us; speedup vs baseline: 1.3785x; 1.3785x over previous
//
#include <hip/hip_runtime.h>

// Resample 48k -> 10k: up=5, down=24, 481-tap FIR.
// y[5k+d] = sum_{c=0..14,u=0..7} T[c*40+d*8+u] * x[24k-48+8c+u]
// T[c*40+d*8+u] = 5*h[24d+480-5*(8c+u)]  (c,d compile-time -> SGPR s_load)
//
// R10 (resubmit; infra failure last round): maximize resident waves
// (evidence: time ~ 1/waves across R2/R3/R8/R9; DS width, prefetch, tap
// source all null). 128-thr blocks, 2 waves SPLIT ONE 64-k TILE by even/odd
// chunks (33 vs 32 active tap groups — balanced), so LDS/block stays 10.2 kB
// -> 16 blocks/CU = 32 waves/CU (HW cap) vs 19 before.
// c stays wave-uniform+compile-time -> SGPR taps + v_pk_fma_f32 retained.
// Wave1 writes 5 scalar partials to LDS; wave0 combines + stores.
// __launch_bounds__(128,8) caps VGPR at 64 (no occupancy loss from regs).

#define NIN   1440000
#define NOUTR 300000
#define NROWS 32
#define KTOT  60000
#define BKW   64                        // k per block (shared by both waves)
#define NBX   ((KTOT + BKW - 1) / BKW)  // 938
#define TILE  1632                      // 24*63 + 120
#define NV4   (TILE / 4)                // 408 float4s
#define PADT  2040                      // swizzled tile floats (1.25x)
#define LDSN  (PADT + 512)              // + 64*8 reduce floats = 10208 B
#define TAPN  600

__global__ void prep_taps_kernel(const float* __restrict__ h, float* __restrict__ T) {
    int i = blockIdx.x * blockDim.x + threadIdx.x;
    if (i < TAPN) {
        int u = i & 7;
        int d = (i >> 3) % 5;
        int c = i / 40;
        int t = 24 * d + 480 - 5 * (c * 8 + u);
        T[i] = (t >= 0 && t <= 480) ? h[t] * 5.0f : 0.0f;
    }
}

template<int C>
__device__ __forceinline__ void chunk_mac(const float* __restrict__ L,
                                          const float* __restrict__ T,
                                          int base, float2 acc[5]) {
    const int m0 = base + 10 * C;       // e0=24*lane+8C -> m=e0+(e0>>3)*2
    const float2 xv0 = *reinterpret_cast<const float2*>(L + m0);
    const float2 xv1 = *reinterpret_cast<const float2*>(L + m0 + 2);
    const float2 xv2 = *reinterpret_cast<const float2*>(L + m0 + 4);
    const float2 xv3 = *reinterpret_cast<const float2*>(L + m0 + 6);
    #pragma unroll
    for (int d = 0; d < 5; ++d) {
        // compile-time skip of all-zero tap groups (C,d constants)
        if (24 * d + 480 - 40 * C >= 0 && 24 * d + 445 - 40 * C <= 480) {
            const float2* __restrict__ tp =
                reinterpret_cast<const float2*>(T + C * 40 + d * 8);
            const float2 t0 = tp[0], t1 = tp[1], t2 = tp[2], t3 = tp[3];
            asm("v_pk_fma_f32 %0, %1, %2, %0" : "+v"(acc[d]) : "s"(t0), "v"(xv0));
            asm("v_pk_fma_f32 %0, %1, %2, %0" : "+v"(acc[d]) : "s"(t1), "v"(xv1));
            asm("v_pk_fma_f32 %0, %1, %2, %0" : "+v"(acc[d]) : "s"(t2), "v"(xv2));
            asm("v_pk_fma_f32 %0, %1, %2, %0" : "+v"(acc[d]) : "s"(t3), "v"(xv3));
        }
    }
}

__global__ __launch_bounds__(128, 8) void resample_kernel(
    const float* __restrict__ x, const float* __restrict__ T, float* __restrict__ y)
{
    __shared__ float lds[LDSN];
    const int tid  = threadIdx.x;
    const int lane = tid & 63;
    const int wid  = tid >> 6;              // wave-uniform 0/1
    const int row  = blockIdx.y;
    const int k0   = blockIdx.x * BKW;
    const float* __restrict__ xr = x + (size_t)row * NIN;
    const int g0 = 24 * k0 - 48;            // multiple of 4 -> 16B-aligned

    // Stage shared tile (both waves), pad-2-per-8 swizzle (m = e + (e>>3)*2).
    if (g0 >= 0 && g0 + TILE <= NIN) {      // interior fast path
        #pragma unroll
        for (int j = 0; j < 4; ++j) {
            const int i4 = tid + 128 * j;
            if (j < 3 || i4 < NV4) {
                const int e = i4 * 4;
                const float4 v = *reinterpret_cast<const float4*>(xr + g0 + e);
                const int m = e + ((e >> 3) << 1);
                *reinterpret_cast<float2*>(&lds[m])     = make_float2(v.x, v.y);
                *reinterpret_cast<float2*>(&lds[m + 2]) = make_float2(v.z, v.w);
            }
        }
    } else {                                 // first/last blocks only
        #pragma unroll
        for (int j = 0; j < 4; ++j) {
            const int i4 = tid + 128 * j;
            if (j < 3 || i4 < NV4) {
                const int e = i4 * 4;
                const int g = g0 + e;
                float4 v;
                v.x = ((unsigned)(g + 0) < NIN) ? xr[g + 0] : 0.0f;
                v.y = ((unsigned)(g + 1) < NIN) ? xr[g + 1] : 0.0f;
                v.z = ((unsigned)(g + 2) < NIN) ? xr[g + 2] : 0.0f;
                v.w = ((unsigned)(g + 3) < NIN) ? xr[g + 3] : 0.0f;
                const int m = e + ((e >> 3) << 1);
                *reinterpret_cast<float2*>(&lds[m])     = make_float2(v.x, v.y);
                *reinterpret_cast<float2*>(&lds[m + 2]) = make_float2(v.z, v.w);
            }
        }
    }
    __syncthreads();

    float2 acc[5];
    #pragma unroll
    for (int d = 0; d < 5; ++d) acc[d] = make_float2(0.f, 0.f);

    const int base = 30 * lane;
    if (wid == 0) {                          // even chunks: 33 active groups
        chunk_mac< 0>(lds, T, base, acc);
        chunk_mac< 2>(lds, T, base, acc);
        chunk_mac< 4>(lds, T, base, acc);
        chunk_mac< 6>(lds, T, base, acc);
        chunk_mac< 8>(lds, T, base, acc);
        chunk_mac<10>(lds, T, base, acc);
        chunk_mac<12>(lds, T, base, acc);
        chunk_mac<14>(lds, T, base, acc);
    } else {                                 // odd chunks: 32 active groups
        chunk_mac< 1>(lds, T, base, acc);
        chunk_mac< 3>(lds, T, base, acc);
        chunk_mac< 5>(lds, T, base, acc);
        chunk_mac< 7>(lds, T, base, acc);
        chunk_mac< 9>(lds, T, base, acc);
        chunk_mac<11>(lds, T, base, acc);
        chunk_mac<13>(lds, T, base, acc);
    }

    if (wid == 1) {                          // write partials (scalars)
        float* __restrict__ rp = &lds[PADT + 8 * lane];
        float4 r;
        r.x = acc[0].x + acc[0].y;
        r.y = acc[1].x + acc[1].y;
        r.z = acc[2].x + acc[2].y;
        r.w = acc[3].x + acc[3].y;
        *reinterpret_cast<float4*>(rp) = r;  // 8160 + 32*lane: 16B-aligned ✓
        rp[4] = acc[4].x + acc[4].y;
    }
    __syncthreads();

    if (wid == 0) {
        const int k = k0 + lane;
        if (k < KTOT) {
            const float* __restrict__ rp = &lds[PADT + 8 * lane];
            const float4 r = *reinterpret_cast<const float4*>(rp);
            const float r4 = rp[4];
            float* __restrict__ yr = y + (size_t)row * NOUTR + (size_t)5 * k;
            yr[0] = acc[0].x + acc[0].y + r.x;
            yr[1] = acc[1].x + acc[1].y + r.y;
            yr[2] = acc[2].x + acc[2].y + r.z;
            yr[3] = acc[3].x + acc[3].y + r.w;
            yr[4] = acc[4].x + acc[4].y + r4;
        }
    }
}

extern "C" void kernel_launch(void* const* d_in, const int* in_sizes, int n_in,
                              void* d_out, int out_size, void* d_ws, size_t ws_size,
                              hipStream_t stream) {
    const float* x = (const float*)d_in[0];
    const float* h = (const float*)d_in[1];   // 481 taps
    float* y = (float*)d_out;                 // 32 x 300000 f32
    float* T = (float*)d_ws;                  // 600 floats of scratch

    prep_taps_kernel<<<3, 256, 0, stream>>>(h, T);
    dim3 grid(NBX, NROWS);                    // 938 x 32 two-wave blocks
    resample_kernel<<<grid, 128, 0, stream>>>(x, T, y);
}